// Round 10
// baseline (211.137 us; speedup 1.0000x reference)
//
#include <hip/hip_runtime.h>

#define E_EDGES 1000000
#define EBLK (E_EDGES / 64)      // 15625
#define NNODES 100000
#define NGBLK ((NNODES + 63) / 64) // 1563
#define LATENT 128
#define DIN 288
#define H1DIM 128
#define PAD1 136                 // halfs; 272 B stride, 16B-mult
#define PAD2 66                  // halfs; scalar b16 access only
#define PADA 296                 // mono fallback tile stride

// ---- split-path ws layout (bf16 element offsets) ----
#define WT1A 0                   // [128][128] n-major: wt1a[n][k]=W1[k][n]
#define WT1B 16384               // [128][128]: wt1b[n][k]=W1[128+k][n]
#define WT2S 32768               // [64][128]:  wt2[f][k]=W2[k][f]
#define TPOFF 40960              // f32[13][128] lives here (3328 bf16-elems)
#define UOFF 44288
#define UROWS 100032
#define VOFF (UOFF + UROWS * 128)
#define WS_SPLIT ((size_t)(VOFF + UROWS * 128) * 2)   // ~51.3 MB

// ---- mono fallback layout ----
#define MW1 0                    // [128][288]
#define MW2 36864                // [64][128]

typedef __bf16 v8bf __attribute__((ext_vector_type(8)));
typedef __bf16 v4bf __attribute__((ext_vector_type(4)));
typedef __bf16 v2bf __attribute__((ext_vector_type(2)));
typedef float  v4f  __attribute__((ext_vector_type(4)));

__device__ __forceinline__ void cvt_store4(__bf16* p, float4 v) {
    v4bf o;
    o[0] = (__bf16)v.x; o[1] = (__bf16)v.y; o[2] = (__bf16)v.z; o[3] = (__bf16)v.w;
    *(v4bf*)p = o;
}

// ===================== split path =====================

// weights transpose + T' table (T'[b][n] = b1[n] + sum_k emb[b][k]*W1[256+k][n])
__global__ void prep_split(const float* __restrict__ W1, const float* __restrict__ W2,
                           const float* __restrict__ embed, const float* __restrict__ b1,
                           __bf16* __restrict__ ws) {
    int i = blockIdx.x * 256 + threadIdx.x;
    if (i < 16384) {                       // wt1a
        int n = i >> 7, k = i & 127;
        ws[WT1A + i] = (__bf16)W1[k * 128 + n];
    } else if (i < 32768) {                // wt1b
        int idx = i - 16384;
        int n = idx >> 7, k = idx & 127;
        ws[WT1B + idx] = (__bf16)W1[(128 + k) * 128 + n];
    } else if (i < 40960) {                // wt2
        int idx = i - 32768;
        int f = idx >> 7, k = idx & 127;
        ws[WT2S + idx] = (__bf16)W2[k * 64 + f];
    } else if (i < 40960 + 1664) {         // T' (f32)
        int idx = i - 40960;
        int b = idx >> 7, n = idx & 127;
        float s = b1[n];
        #pragma unroll
        for (int k = 0; k < 32; ++k)
            s += embed[b * 32 + k] * W1[(256 + k) * 128 + n];
        ((float*)(ws + TPOFF))[idx] = s;
    }
}

// node-major GEMM: U = z @ W1a, V = z @ W1b  (64 nodes/block, K=128)
__global__ __launch_bounds__(256, 4) void node_gemm(
    const float* __restrict__ z, const __bf16* __restrict__ ws, __bf16* __restrict__ wsm)
{
    __shared__ __align__(16) __bf16 sA[64 * PAD1];
    const int tid = threadIdx.x;
    const int n0 = blockIdx.x * 64;

    // stage 64 node rows (coalesced, f32 -> bf16)
    {
        const int r = tid >> 2, j = tid & 3;
        int nd = n0 + r; if (nd >= NNODES) nd = NNODES - 1;   // clamp (not stored)
        const float4* zs = (const float4*)(z + (size_t)nd * LATENT);
        __bf16* rowp = &sA[r * PAD1];
        #pragma unroll
        for (int i = 0; i < 8; ++i) { int p = j + 4 * i; cvt_store4(rowp + p * 4, zs[p]); }
    }
    __syncthreads();

    const int wave = tid >> 6, lane = tid & 63, quad = lane >> 4, col16 = lane & 15;
    v4f zero4 = {0.f, 0.f, 0.f, 0.f};

    #pragma unroll
    for (int pass = 0; pass < 2; ++pass) {
        const __bf16* wt = ws + (pass == 0 ? WT1A : WT1B);
        __bf16* outp = wsm + (pass == 0 ? UOFF : VOFF);
        const __bf16* w1p0 = wt + (size_t)(wave * 32 + 2 * col16) * 128;
        const __bf16* w1p1 = w1p0 + 128;
        v4f acc[4][2];
        #pragma unroll
        for (int mt = 0; mt < 4; ++mt) { acc[mt][0] = zero4; acc[mt][1] = zero4; }
        #pragma unroll
        for (int ks = 0; ks < 4; ++ks) {
            int k0 = ks * 32 + quad * 8;
            v8bf a0 = *(const v8bf*)&sA[(0 * 16 + col16) * PAD1 + k0];
            v8bf a1 = *(const v8bf*)&sA[(1 * 16 + col16) * PAD1 + k0];
            v8bf a2 = *(const v8bf*)&sA[(2 * 16 + col16) * PAD1 + k0];
            v8bf a3 = *(const v8bf*)&sA[(3 * 16 + col16) * PAD1 + k0];
            v8bf bb0 = *(const v8bf*)&w1p0[k0];
            v8bf bb1 = *(const v8bf*)&w1p1[k0];
            acc[0][0] = __builtin_amdgcn_mfma_f32_16x16x32_bf16(a0, bb0, acc[0][0], 0, 0, 0);
            acc[1][0] = __builtin_amdgcn_mfma_f32_16x16x32_bf16(a1, bb0, acc[1][0], 0, 0, 0);
            acc[2][0] = __builtin_amdgcn_mfma_f32_16x16x32_bf16(a2, bb0, acc[2][0], 0, 0, 0);
            acc[3][0] = __builtin_amdgcn_mfma_f32_16x16x32_bf16(a3, bb0, acc[3][0], 0, 0, 0);
            acc[0][1] = __builtin_amdgcn_mfma_f32_16x16x32_bf16(a0, bb1, acc[0][1], 0, 0, 0);
            acc[1][1] = __builtin_amdgcn_mfma_f32_16x16x32_bf16(a1, bb1, acc[1][1], 0, 0, 0);
            acc[2][1] = __builtin_amdgcn_mfma_f32_16x16x32_bf16(a2, bb1, acc[2][1], 0, 0, 0);
            acc[3][1] = __builtin_amdgcn_mfma_f32_16x16x32_bf16(a3, bb1, acc[3][1], 0, 0, 0);
        }
        // store pair-packed cols (2c, 2c+1)
        #pragma unroll
        for (int mt = 0; mt < 4; ++mt) {
            #pragma unroll
            for (int rr = 0; rr < 4; ++rr) {
                int m = mt * 16 + quad * 4 + rr;
                int nd = n0 + m;
                if (nd < NNODES) {
                    v2bf o;
                    o[0] = (__bf16)acc[mt][0][rr];
                    o[1] = (__bf16)acc[mt][1][rr];
                    *(v2bf*)&outp[(size_t)nd * 128 + wave * 32 + 2 * col16] = o;
                }
            }
        }
    }
}

// edge kernel: gather U[src]+V[dst]+T'[b] -> relu -> sH1 -> GEMM2 -> GEMM3+softplus
// LDS: 17,408 (sH1, later aliased by sH2) + 516 = 17,924 B -> 8 blocks/CU (100% occ cap)
__global__ __launch_bounds__(256, 8) void edge_kernel(
    const int* __restrict__ eidx, const int* __restrict__ bt,
    const float* __restrict__ b2, const float* __restrict__ W3,
    const float* __restrict__ b3, const __bf16* __restrict__ ws,
    float* __restrict__ out)
{
    __shared__ __align__(16) __bf16 sbuf[64 * PAD1];
    __shared__ float sb2[64];
    __shared__ float sw3[64];
    __shared__ float sb3s;
    __bf16* sH1 = sbuf;                 // [64][PAD1] phase 1
    __bf16* sH2 = sbuf;                 // [64][PAD2] phase 2 (aliased after barrier)

    const __bf16* wt2 = ws + WT2S;
    const float*  tpf = (const float*)(ws + TPOFF);
    const __bf16* U   = ws + UOFF;
    const __bf16* V   = ws + VOFF;

    const int tid = threadIdx.x;
    const int e0 = blockIdx.x * 64;

    if (tid < 64) sb2[tid] = b2[tid];
    else if (tid < 128) sw3[tid - 64] = W3[tid - 64];
    else if (tid == 128) sb3s = b3[0];

    // ---- gather + combine: thread owns 32 halfs of one edge row ----
    {
        const int r = tid >> 2, j = tid & 3;
        const int e = e0 + r;
        const int isrc = eidx[e];
        const int idst = eidx[E_EDGES + e];
        const int ib   = bt[e];
        const v8bf* up = (const v8bf*)(U + (size_t)isrc * 128);
        const v8bf* vp = (const v8bf*)(V + (size_t)idst * 128);
        const float4* tp = (const float4*)(tpf + ib * 128);
        __bf16* rowp = &sH1[r * PAD1];
        v8bf u[4], v[4];
        #pragma unroll
        for (int i = 0; i < 4; ++i) u[i] = up[j + 4 * i];
        #pragma unroll
        for (int i = 0; i < 4; ++i) v[i] = vp[j + 4 * i];
        #pragma unroll
        for (int i = 0; i < 4; ++i) {
            int p = j + 4 * i;                   // chunk of 8 feats
            float4 t0 = tp[p * 2], t1 = tp[p * 2 + 1];
            v8bf o;
            o[0] = (__bf16)fmaxf((float)u[i][0] + (float)v[i][0] + t0.x, 0.f);
            o[1] = (__bf16)fmaxf((float)u[i][1] + (float)v[i][1] + t0.y, 0.f);
            o[2] = (__bf16)fmaxf((float)u[i][2] + (float)v[i][2] + t0.z, 0.f);
            o[3] = (__bf16)fmaxf((float)u[i][3] + (float)v[i][3] + t0.w, 0.f);
            o[4] = (__bf16)fmaxf((float)u[i][4] + (float)v[i][4] + t1.x, 0.f);
            o[5] = (__bf16)fmaxf((float)u[i][5] + (float)v[i][5] + t1.y, 0.f);
            o[6] = (__bf16)fmaxf((float)u[i][6] + (float)v[i][6] + t1.z, 0.f);
            o[7] = (__bf16)fmaxf((float)u[i][7] + (float)v[i][7] + t1.w, 0.f);
            *(v8bf*)(rowp + p * 8) = o;
        }
    }
    __syncthreads();                    // B1: sH1 ready

    const int wave = tid >> 6, lane = tid & 63, quad = lane >> 4, col16 = lane & 15;
    v4f zero4 = {0.f, 0.f, 0.f, 0.f};

    // ---- GEMM2: wave owns feat wave*16+col16; A=sH1 LDS, B=wt2 global (1 stream) ----
    v4f acc2[4];
    #pragma unroll
    for (int mt = 0; mt < 4; ++mt) acc2[mt] = zero4;

    const __bf16* w2p = wt2 + (size_t)(wave * 16 + col16) * H1DIM;
    #pragma unroll
    for (int ks = 0; ks < 4; ++ks) {
        int k0 = ks * 32 + quad * 8;
        v8bf bb = *(const v8bf*)&w2p[k0];
        #pragma unroll
        for (int mt = 0; mt < 4; ++mt) {
            v8bf aa = *(const v8bf*)&sH1[(mt * 16 + col16) * PAD1 + k0];
            acc2[mt] = __builtin_amdgcn_mfma_f32_16x16x32_bf16(aa, bb, acc2[mt], 0, 0, 0);
        }
    }
    __syncthreads();                    // B2: sH1 reads done (sH2 aliases sH1)

    // ---- epi2: bias+relu -> sH2 edge-major ----
    {
        int n = wave * 16 + col16;
        float bias = sb2[n];
        #pragma unroll
        for (int mt = 0; mt < 4; ++mt) {
            #pragma unroll
            for (int rr = 0; rr < 4; ++rr) {
                int m = mt * 16 + quad * 4 + rr;
                sH2[m * PAD2 + n] = (__bf16)fmaxf(acc2[mt][rr] + bias, 0.f);
            }
        }
    }
    __syncthreads();                    // B3: sH2 ready

    // ---- GEMM3 + softplus ----
    {
        int row = tid >> 2;
        int q   = tid & 3;
        float s = 0.f;
        #pragma unroll
        for (int kk = 0; kk < 16; ++kk) {
            int k = q * 16 + kk;
            s += (float)sH2[row * PAD2 + k] * sw3[k];
        }
        s += __shfl_xor(s, 1);
        s += __shfl_xor(s, 2);
        if (q == 0) {
            float x = s + sb3s;
            out[e0 + row] = fmaxf(x, 0.f) + log1pf(expf(-fabsf(x)));
        }
    }
}

// ===================== mono fallback (R4 f32 path) =====================

__global__ void prep_mono(const float* __restrict__ W1, const float* __restrict__ W2,
                          __bf16* __restrict__ ws) {
    int i = blockIdx.x * 256 + threadIdx.x;
    if (i < DIN * H1DIM) {
        int n = i / DIN, k = i - n * DIN;
        ws[MW1 + i] = (__bf16)W1[k * H1DIM + n];
    }
    if (i < H1DIM * 64) {
        int n = i / H1DIM, k = i - n * H1DIM;
        ws[MW2 + i] = (__bf16)W2[k * 64 + n];
    }
}

__global__ __launch_bounds__(256, 4) void fused_mono(
    const float* __restrict__ z, const int* __restrict__ eidx,
    const int* __restrict__ bt, const float* __restrict__ embed,
    const float* __restrict__ b1, const float* __restrict__ b2,
    const float* __restrict__ W3, const float* __restrict__ b3,
    const __bf16* __restrict__ ws, float* __restrict__ out)
{
    __shared__ __align__(16) __bf16 sbuf[64 * PADA];
    __shared__ __bf16 sH2[64 * PAD2];
    __shared__ float sb1[H1DIM];
    __shared__ float sb2[64];
    __shared__ float sw3[64];
    __shared__ float sb3s;
    __bf16* sA  = sbuf;
    __bf16* sH1 = sbuf;

    const __bf16* wt1 = ws + MW1;
    const __bf16* wt2 = ws + MW2;
    const int tid = threadIdx.x;
    const int e0 = blockIdx.x * 64;

    if (tid < 128) sb1[tid] = b1[tid];
    else if (tid < 192) sb2[tid - 128] = b2[tid - 128];
    else { int k = tid - 192; sw3[k] = W3[k]; if (k == 0) sb3s = b3[0]; }

    {
        const int r = tid >> 2, j = tid & 3;
        const int e = e0 + r;
        const int isrc = eidx[e];
        const int idst = eidx[E_EDGES + e];
        const int ib   = bt[e];
        const float4* zs = (const float4*)(z + (size_t)isrc * LATENT);
        const float4* zd = (const float4*)(z + (size_t)idst * LATENT);
        const float4* em = (const float4*)(embed + (size_t)ib * 32);
        __bf16* rowp = &sA[r * PADA];
        #pragma unroll
        for (int i = 0; i < 8; ++i) { int p = j + 4 * i; cvt_store4(rowp + p * 4, zs[p]); }
        #pragma unroll
        for (int i = 0; i < 8; ++i) { int p = j + 4 * i; cvt_store4(rowp + 128 + p * 4, zd[p]); }
        #pragma unroll
        for (int i = 0; i < 2; ++i) { int p = j + 4 * i; cvt_store4(rowp + 256 + p * 4, em[p]); }
    }
    __syncthreads();

    const int wave = tid >> 6, lane = tid & 63, quad = lane >> 4, col16 = lane & 15;
    v4f zero4 = {0.f, 0.f, 0.f, 0.f};
    v4f acc[4][2];
    #pragma unroll
    for (int mt = 0; mt < 4; ++mt) { acc[mt][0] = zero4; acc[mt][1] = zero4; }

    const __bf16* w1p0 = wt1 + (size_t)(wave * 32 + col16) * DIN;
    const __bf16* w1p1 = wt1 + (size_t)(wave * 32 + 16 + col16) * DIN;

    #pragma unroll
    for (int ks = 0; ks < 9; ++ks) {
        int k0 = ks * 32 + quad * 8;
        v8bf a0 = *(const v8bf*)&sA[(0 * 16 + col16) * PADA + k0];
        v8bf a1 = *(const v8bf*)&sA[(1 * 16 + col16) * PADA + k0];
        v8bf a2 = *(const v8bf*)&sA[(2 * 16 + col16) * PADA + k0];
        v8bf a3 = *(const v8bf*)&sA[(3 * 16 + col16) * PADA + k0];
        v8bf bb0 = *(const v8bf*)&w1p0[k0];
        v8bf bb1 = *(const v8bf*)&w1p1[k0];
        acc[0][0] = __builtin_amdgcn_mfma_f32_16x16x32_bf16(a0, bb0, acc[0][0], 0, 0, 0);
        acc[1][0] = __builtin_amdgcn_mfma_f32_16x16x32_bf16(a1, bb0, acc[1][0], 0, 0, 0);
        acc[2][0] = __builtin_amdgcn_mfma_f32_16x16x32_bf16(a2, bb0, acc[2][0], 0, 0, 0);
        acc[3][0] = __builtin_amdgcn_mfma_f32_16x16x32_bf16(a3, bb0, acc[3][0], 0, 0, 0);
        acc[0][1] = __builtin_amdgcn_mfma_f32_16x16x32_bf16(a0, bb1, acc[0][1], 0, 0, 0);
        acc[1][1] = __builtin_amdgcn_mfma_f32_16x16x32_bf16(a1, bb1, acc[1][1], 0, 0, 0);
        acc[2][1] = __builtin_amdgcn_mfma_f32_16x16x32_bf16(a2, bb1, acc[2][1], 0, 0, 0);
        acc[3][1] = __builtin_amdgcn_mfma_f32_16x16x32_bf16(a3, bb1, acc[3][1], 0, 0, 0);
    }
    __syncthreads();

    #pragma unroll
    for (int j = 0; j < 2; ++j) {
        int n = wave * 32 + j * 16 + col16;
        float bias = sb1[n];
        #pragma unroll
        for (int mt = 0; mt < 4; ++mt) {
            #pragma unroll
            for (int r = 0; r < 4; ++r) {
                int m = mt * 16 + quad * 4 + r;
                sH1[m * PAD1 + n] = (__bf16)fmaxf(acc[mt][j][r] + bias, 0.f);
            }
        }
    }
    __syncthreads();

    v4f acc2[4];
    #pragma unroll
    for (int mt = 0; mt < 4; ++mt) acc2[mt] = zero4;
    const __bf16* w2p = wt2 + (size_t)(wave * 16 + col16) * H1DIM;
    #pragma unroll
    for (int ks = 0; ks < 4; ++ks) {
        int k0 = ks * 32 + quad * 8;
        v8bf bb = *(const v8bf*)&w2p[k0];
        #pragma unroll
        for (int mt = 0; mt < 4; ++mt) {
            v8bf aa = *(const v8bf*)&sH1[(mt * 16 + col16) * PAD1 + k0];
            acc2[mt] = __builtin_amdgcn_mfma_f32_16x16x32_bf16(aa, bb, acc2[mt], 0, 0, 0);
        }
    }
    {
        int n = wave * 16 + col16;
        float bias = sb2[n];
        #pragma unroll
        for (int mt = 0; mt < 4; ++mt) {
            #pragma unroll
            for (int rr = 0; rr < 4; ++rr) {
                int m = mt * 16 + quad * 4 + rr;
                sH2[m * PAD2 + n] = (__bf16)fmaxf(acc2[mt][rr] + bias, 0.f);
            }
        }
    }
    __syncthreads();
    {
        int row = tid >> 2, q = tid & 3;
        float s = 0.f;
        #pragma unroll
        for (int kk = 0; kk < 16; ++kk) {
            int k = q * 16 + kk;
            s += (float)sH2[row * PAD2 + k] * sw3[k];
        }
        s += __shfl_xor(s, 1);
        s += __shfl_xor(s, 2);
        if (q == 0) {
            float x = s + sb3s;
            out[e0 + row] = fmaxf(x, 0.f) + log1pf(expf(-fabsf(x)));
        }
    }
}

extern "C" void kernel_launch(void* const* d_in, const int* in_sizes, int n_in,
                              void* d_out, int out_size, void* d_ws, size_t ws_size,
                              hipStream_t stream) {
    const float* z     = (const float*)d_in[0];
    const int*   eidx  = (const int*)d_in[1];
    const int*   btyp  = (const int*)d_in[2];
    const float* embed = (const float*)d_in[3];
    const float* W1    = (const float*)d_in[4];
    const float* b1    = (const float*)d_in[5];
    const float* W2    = (const float*)d_in[6];
    const float* b2    = (const float*)d_in[7];
    const float* W3    = (const float*)d_in[8];
    const float* b3    = (const float*)d_in[9];
    float* out = (float*)d_out;
    __bf16* ws = (__bf16*)d_ws;

    if (ws_size >= WS_SPLIT) {
        prep_split<<<167, 256, 0, stream>>>(W1, W2, embed, b1, ws);
        node_gemm<<<NGBLK, 256, 0, stream>>>(z, ws, ws);
        edge_kernel<<<EBLK, 256, 0, stream>>>(eidx, btyp, b2, W3, b3, ws, out);
    } else {
        prep_mono<<<(DIN * H1DIM + 255) / 256, 256, 0, stream>>>(W1, W2, ws);
        fused_mono<<<EBLK, 256, 0, stream>>>(z, eidx, btyp, embed,
                                             b1, b2, W3, b3, ws, out);
    }
}

// Round 11
// 208.944 us; speedup vs baseline: 1.0105x; 1.0105x over previous
//
#include <hip/hip_runtime.h>

#define E_EDGES 1000000
#define EBLK (E_EDGES / 64)      // 15625
#define NNODES 100000
#define NGBLK ((NNODES + 63) / 64) // 1563
#define LATENT 128
#define DIN 288
#define H1DIM 128
#define PAD1 136                 // halfs; 272 B stride, 16B-mult
#define PAD2 66                  // halfs; scalar b16 access only
#define PADA 296                 // mono fallback tile stride

// ---- split-path ws layout (bf16 element offsets) ----
#define WT1A 0                   // [128][128] n-major: wt1a[n][k]=W1[k][n]
#define WT1B 16384               // [128][128]: wt1b[n][k]=W1[128+k][n]
#define WT2S 32768               // [64][128]:  wt2[f][k]=W2[k][f]
#define TPOFF 40960              // f32[13][128] lives here (3328 bf16-elems)
#define UOFF 44288
#define UROWS 100032
#define VOFF (UOFF + UROWS * 128)
#define WS_SPLIT ((size_t)(VOFF + UROWS * 128) * 2)   // ~51.3 MB

// ---- mono fallback layout ----
#define MW1 0                    // [128][288]
#define MW2 36864                // [64][128]

typedef __bf16 v8bf __attribute__((ext_vector_type(8)));
typedef __bf16 v4bf __attribute__((ext_vector_type(4)));
typedef __bf16 v2bf __attribute__((ext_vector_type(2)));
typedef float  v4f  __attribute__((ext_vector_type(4)));

__device__ __forceinline__ void cvt_store4(__bf16* p, float4 v) {
    v4bf o;
    o[0] = (__bf16)v.x; o[1] = (__bf16)v.y; o[2] = (__bf16)v.z; o[3] = (__bf16)v.w;
    *(v4bf*)p = o;
}

// ===================== split path =====================

// weights transpose + T' table (T'[b][n] = b1[n] + sum_k emb[b][k]*W1[256+k][n])
__global__ void prep_split(const float* __restrict__ W1, const float* __restrict__ W2,
                           const float* __restrict__ embed, const float* __restrict__ b1,
                           __bf16* __restrict__ ws) {
    int i = blockIdx.x * 256 + threadIdx.x;
    if (i < 16384) {                       // wt1a
        int n = i >> 7, k = i & 127;
        ws[WT1A + i] = (__bf16)W1[k * 128 + n];
    } else if (i < 32768) {                // wt1b
        int idx = i - 16384;
        int n = idx >> 7, k = idx & 127;
        ws[WT1B + idx] = (__bf16)W1[(128 + k) * 128 + n];
    } else if (i < 40960) {                // wt2
        int idx = i - 32768;
        int f = idx >> 7, k = idx & 127;
        ws[WT2S + idx] = (__bf16)W2[k * 64 + f];
    } else if (i < 40960 + 1664) {         // T' (f32)
        int idx = i - 40960;
        int b = idx >> 7, n = idx & 127;
        float s = b1[n];
        #pragma unroll
        for (int k = 0; k < 32; ++k)
            s += embed[b * 32 + k] * W1[(256 + k) * 128 + n];
        ((float*)(ws + TPOFF))[idx] = s;
    }
}

// node-major GEMM: U = z @ W1a, V = z @ W1b  (64 nodes/block, K=128)
// Output staged through LDS -> fully coalesced contiguous 16 KB store per pass.
__global__ __launch_bounds__(256, 4) void node_gemm(
    const float* __restrict__ z, const __bf16* __restrict__ ws, __bf16* __restrict__ wsm)
{
    __shared__ __align__(16) __bf16 sA[64 * PAD1];
    __shared__ __align__(16) __bf16 sOut[64 * PAD1];
    const int tid = threadIdx.x;
    const int n0 = blockIdx.x * 64;

    // stage 64 node rows (coalesced, f32 -> bf16)
    {
        const int r = tid >> 2, j = tid & 3;
        int nd = n0 + r; if (nd >= NNODES) nd = NNODES - 1;   // clamp (not stored)
        const float4* zs = (const float4*)(z + (size_t)nd * LATENT);
        __bf16* rowp = &sA[r * PAD1];
        #pragma unroll
        for (int i = 0; i < 8; ++i) { int p = j + 4 * i; cvt_store4(rowp + p * 4, zs[p]); }
    }
    __syncthreads();

    const int wave = tid >> 6, lane = tid & 63, quad = lane >> 4, col16 = lane & 15;
    v4f zero4 = {0.f, 0.f, 0.f, 0.f};

    #pragma unroll
    for (int pass = 0; pass < 2; ++pass) {
        const __bf16* wt = ws + (pass == 0 ? WT1A : WT1B);
        __bf16* outp = wsm + (pass == 0 ? UOFF : VOFF) + (size_t)n0 * 128;
        const __bf16* w1p0 = wt + (size_t)(wave * 32 + 2 * col16) * 128;
        const __bf16* w1p1 = w1p0 + 128;
        v4f acc[4][2];
        #pragma unroll
        for (int mt = 0; mt < 4; ++mt) { acc[mt][0] = zero4; acc[mt][1] = zero4; }
        #pragma unroll
        for (int ks = 0; ks < 4; ++ks) {
            int k0 = ks * 32 + quad * 8;
            v8bf a0 = *(const v8bf*)&sA[(0 * 16 + col16) * PAD1 + k0];
            v8bf a1 = *(const v8bf*)&sA[(1 * 16 + col16) * PAD1 + k0];
            v8bf a2 = *(const v8bf*)&sA[(2 * 16 + col16) * PAD1 + k0];
            v8bf a3 = *(const v8bf*)&sA[(3 * 16 + col16) * PAD1 + k0];
            v8bf bb0 = *(const v8bf*)&w1p0[k0];
            v8bf bb1 = *(const v8bf*)&w1p1[k0];
            acc[0][0] = __builtin_amdgcn_mfma_f32_16x16x32_bf16(a0, bb0, acc[0][0], 0, 0, 0);
            acc[1][0] = __builtin_amdgcn_mfma_f32_16x16x32_bf16(a1, bb0, acc[1][0], 0, 0, 0);
            acc[2][0] = __builtin_amdgcn_mfma_f32_16x16x32_bf16(a2, bb0, acc[2][0], 0, 0, 0);
            acc[3][0] = __builtin_amdgcn_mfma_f32_16x16x32_bf16(a3, bb0, acc[3][0], 0, 0, 0);
            acc[0][1] = __builtin_amdgcn_mfma_f32_16x16x32_bf16(a0, bb1, acc[0][1], 0, 0, 0);
            acc[1][1] = __builtin_amdgcn_mfma_f32_16x16x32_bf16(a1, bb1, acc[1][1], 0, 0, 0);
            acc[2][1] = __builtin_amdgcn_mfma_f32_16x16x32_bf16(a2, bb1, acc[2][1], 0, 0, 0);
            acc[3][1] = __builtin_amdgcn_mfma_f32_16x16x32_bf16(a3, bb1, acc[3][1], 0, 0, 0);
        }
        // epi: pair-packed (cols 2c,2c+1) into LDS staging tile
        #pragma unroll
        for (int mt = 0; mt < 4; ++mt) {
            #pragma unroll
            for (int rr = 0; rr < 4; ++rr) {
                int m = mt * 16 + quad * 4 + rr;
                v2bf o;
                o[0] = (__bf16)acc[mt][0][rr];
                o[1] = (__bf16)acc[mt][1][rr];
                *(v2bf*)&sOut[m * PAD1 + wave * 32 + 2 * col16] = o;
            }
        }
        __syncthreads();                 // sOut ready
        // coalesced store: block's tile is one contiguous 16 KB range
        {
            int base = tid * 8;          // half index within 64x128 tile
            #pragma unroll
            for (int i = 0; i < 4; ++i) {
                int idx = base + i * 2048;            // 0..8191
                int m = idx >> 7, c = idx & 127;
                v8bf vv = *(const v8bf*)&sOut[m * PAD1 + c];
                *(v8bf*)&outp[idx] = vv;              // rows >= NNODES land in UROWS slack
            }
        }
        __syncthreads();                 // sOut reads done before next pass writes
    }
}

// edge kernel: gather U[src]+V[dst]+T'[b] -> relu -> sH1 -> GEMM2 -> GEMM3+softplus
// LDS: 17,408 (sH1, later aliased by sH2) + 516 = 17,924 B -> 8 blocks/CU
__global__ __launch_bounds__(256, 8) void edge_kernel(
    const int* __restrict__ eidx, const int* __restrict__ bt,
    const float* __restrict__ b2, const float* __restrict__ W3,
    const float* __restrict__ b3, const __bf16* __restrict__ ws,
    float* __restrict__ out)
{
    __shared__ __align__(16) __bf16 sbuf[64 * PAD1];
    __shared__ float sb2[64];
    __shared__ float sw3[64];
    __shared__ float sb3s;
    __bf16* sH1 = sbuf;                 // [64][PAD1] phase 1
    __bf16* sH2 = sbuf;                 // [64][PAD2] phase 2 (aliased after barrier)

    const __bf16* wt2 = ws + WT2S;
    const float*  tpf = (const float*)(ws + TPOFF);
    const __bf16* U   = ws + UOFF;
    const __bf16* V   = ws + VOFF;

    const int tid = threadIdx.x;
    const int e0 = blockIdx.x * 64;

    if (tid < 64) sb2[tid] = b2[tid];
    else if (tid < 128) sw3[tid - 64] = W3[tid - 64];
    else if (tid == 128) sb3s = b3[0];

    // ---- gather + combine: thread owns 32 halfs of one edge row ----
    {
        const int r = tid >> 2, j = tid & 3;
        const int e = e0 + r;
        const int isrc = eidx[e];
        const int idst = eidx[E_EDGES + e];
        const int ib   = bt[e];
        const v8bf* up = (const v8bf*)(U + (size_t)isrc * 128);
        const v8bf* vp = (const v8bf*)(V + (size_t)idst * 128);
        const float4* tp = (const float4*)(tpf + ib * 128);
        __bf16* rowp = &sH1[r * PAD1];
        v8bf u[4], v[4];
        #pragma unroll
        for (int i = 0; i < 4; ++i) u[i] = up[j + 4 * i];
        #pragma unroll
        for (int i = 0; i < 4; ++i) v[i] = vp[j + 4 * i];
        #pragma unroll
        for (int i = 0; i < 4; ++i) {
            int p = j + 4 * i;                   // chunk of 8 feats
            float4 t0 = tp[p * 2], t1 = tp[p * 2 + 1];
            v8bf o;
            o[0] = (__bf16)fmaxf((float)u[i][0] + (float)v[i][0] + t0.x, 0.f);
            o[1] = (__bf16)fmaxf((float)u[i][1] + (float)v[i][1] + t0.y, 0.f);
            o[2] = (__bf16)fmaxf((float)u[i][2] + (float)v[i][2] + t0.z, 0.f);
            o[3] = (__bf16)fmaxf((float)u[i][3] + (float)v[i][3] + t0.w, 0.f);
            o[4] = (__bf16)fmaxf((float)u[i][4] + (float)v[i][4] + t1.x, 0.f);
            o[5] = (__bf16)fmaxf((float)u[i][5] + (float)v[i][5] + t1.y, 0.f);
            o[6] = (__bf16)fmaxf((float)u[i][6] + (float)v[i][6] + t1.z, 0.f);
            o[7] = (__bf16)fmaxf((float)u[i][7] + (float)v[i][7] + t1.w, 0.f);
            *(v8bf*)(rowp + p * 8) = o;
        }
    }
    __syncthreads();                    // B1: sH1 ready

    const int wave = tid >> 6, lane = tid & 63, quad = lane >> 4, col16 = lane & 15;
    v4f zero4 = {0.f, 0.f, 0.f, 0.f};

    // ---- GEMM2: wave owns feat wave*16+col16; A=sH1 LDS, B=wt2 global (1 stream) ----
    v4f acc2[4];
    #pragma unroll
    for (int mt = 0; mt < 4; ++mt) acc2[mt] = zero4;

    const __bf16* w2p = wt2 + (size_t)(wave * 16 + col16) * H1DIM;
    #pragma unroll
    for (int ks = 0; ks < 4; ++ks) {
        int k0 = ks * 32 + quad * 8;
        v8bf bb = *(const v8bf*)&w2p[k0];
        #pragma unroll
        for (int mt = 0; mt < 4; ++mt) {
            v8bf aa = *(const v8bf*)&sH1[(mt * 16 + col16) * PAD1 + k0];
            acc2[mt] = __builtin_amdgcn_mfma_f32_16x16x32_bf16(aa, bb, acc2[mt], 0, 0, 0);
        }
    }
    __syncthreads();                    // B2: sH1 reads done (sH2 aliases sH1)

    // ---- epi2: bias+relu -> sH2 edge-major ----
    {
        int n = wave * 16 + col16;
        float bias = sb2[n];
        #pragma unroll
        for (int mt = 0; mt < 4; ++mt) {
            #pragma unroll
            for (int rr = 0; rr < 4; ++rr) {
                int m = mt * 16 + quad * 4 + rr;
                sH2[m * PAD2 + n] = (__bf16)fmaxf(acc2[mt][rr] + bias, 0.f);
            }
        }
    }
    __syncthreads();                    // B3: sH2 ready

    // ---- GEMM3 + softplus ----
    {
        int row = tid >> 2;
        int q   = tid & 3;
        float s = 0.f;
        #pragma unroll
        for (int kk = 0; kk < 16; ++kk) {
            int k = q * 16 + kk;
            s += (float)sH2[row * PAD2 + k] * sw3[k];
        }
        s += __shfl_xor(s, 1);
        s += __shfl_xor(s, 2);
        if (q == 0) {
            float x = s + sb3s;
            out[e0 + row] = fmaxf(x, 0.f) + log1pf(expf(-fabsf(x)));
        }
    }
}

// ===================== mono fallback (R4 f32 path) =====================

__global__ void prep_mono(const float* __restrict__ W1, const float* __restrict__ W2,
                          __bf16* __restrict__ ws) {
    int i = blockIdx.x * 256 + threadIdx.x;
    if (i < DIN * H1DIM) {
        int n = i / DIN, k = i - n * DIN;
        ws[MW1 + i] = (__bf16)W1[k * H1DIM + n];
    }
    if (i < H1DIM * 64) {
        int n = i / H1DIM, k = i - n * H1DIM;
        ws[MW2 + i] = (__bf16)W2[k * 64 + n];
    }
}

__global__ __launch_bounds__(256, 4) void fused_mono(
    const float* __restrict__ z, const int* __restrict__ eidx,
    const int* __restrict__ bt, const float* __restrict__ embed,
    const float* __restrict__ b1, const float* __restrict__ b2,
    const float* __restrict__ W3, const float* __restrict__ b3,
    const __bf16* __restrict__ ws, float* __restrict__ out)
{
    __shared__ __align__(16) __bf16 sbuf[64 * PADA];
    __shared__ __bf16 sH2[64 * PAD2];
    __shared__ float sb1[H1DIM];
    __shared__ float sb2[64];
    __shared__ float sw3[64];
    __shared__ float sb3s;
    __bf16* sA  = sbuf;
    __bf16* sH1 = sbuf;

    const __bf16* wt1 = ws + MW1;
    const __bf16* wt2 = ws + MW2;
    const int tid = threadIdx.x;
    const int e0 = blockIdx.x * 64;

    if (tid < 128) sb1[tid] = b1[tid];
    else if (tid < 192) sb2[tid - 128] = b2[tid - 128];
    else { int k = tid - 192; sw3[k] = W3[k]; if (k == 0) sb3s = b3[0]; }

    {
        const int r = tid >> 2, j = tid & 3;
        const int e = e0 + r;
        const int isrc = eidx[e];
        const int idst = eidx[E_EDGES + e];
        const int ib   = bt[e];
        const float4* zs = (const float4*)(z + (size_t)isrc * LATENT);
        const float4* zd = (const float4*)(z + (size_t)idst * LATENT);
        const float4* em = (const float4*)(embed + (size_t)ib * 32);
        __bf16* rowp = &sA[r * PADA];
        #pragma unroll
        for (int i = 0; i < 8; ++i) { int p = j + 4 * i; cvt_store4(rowp + p * 4, zs[p]); }
        #pragma unroll
        for (int i = 0; i < 8; ++i) { int p = j + 4 * i; cvt_store4(rowp + 128 + p * 4, zd[p]); }
        #pragma unroll
        for (int i = 0; i < 2; ++i) { int p = j + 4 * i; cvt_store4(rowp + 256 + p * 4, em[p]); }
    }
    __syncthreads();

    const int wave = tid >> 6, lane = tid & 63, quad = lane >> 4, col16 = lane & 15;
    v4f zero4 = {0.f, 0.f, 0.f, 0.f};
    v4f acc[4][2];
    #pragma unroll
    for (int mt = 0; mt < 4; ++mt) { acc[mt][0] = zero4; acc[mt][1] = zero4; }

    const __bf16* w1p0 = wt1 + (size_t)(wave * 32 + col16) * DIN;
    const __bf16* w1p1 = wt1 + (size_t)(wave * 32 + 16 + col16) * DIN;

    #pragma unroll
    for (int ks = 0; ks < 9; ++ks) {
        int k0 = ks * 32 + quad * 8;
        v8bf a0 = *(const v8bf*)&sA[(0 * 16 + col16) * PADA + k0];
        v8bf a1 = *(const v8bf*)&sA[(1 * 16 + col16) * PADA + k0];
        v8bf a2 = *(const v8bf*)&sA[(2 * 16 + col16) * PADA + k0];
        v8bf a3 = *(const v8bf*)&sA[(3 * 16 + col16) * PADA + k0];
        v8bf bb0 = *(const v8bf*)&w1p0[k0];
        v8bf bb1 = *(const v8bf*)&w1p1[k0];
        acc[0][0] = __builtin_amdgcn_mfma_f32_16x16x32_bf16(a0, bb0, acc[0][0], 0, 0, 0);
        acc[1][0] = __builtin_amdgcn_mfma_f32_16x16x32_bf16(a1, bb0, acc[1][0], 0, 0, 0);
        acc[2][0] = __builtin_amdgcn_mfma_f32_16x16x32_bf16(a2, bb0, acc[2][0], 0, 0, 0);
        acc[3][0] = __builtin_amdgcn_mfma_f32_16x16x32_bf16(a3, bb0, acc[3][0], 0, 0, 0);
        acc[0][1] = __builtin_amdgcn_mfma_f32_16x16x32_bf16(a0, bb1, acc[0][1], 0, 0, 0);
        acc[1][1] = __builtin_amdgcn_mfma_f32_16x16x32_bf16(a1, bb1, acc[1][1], 0, 0, 0);
        acc[2][1] = __builtin_amdgcn_mfma_f32_16x16x32_bf16(a2, bb1, acc[2][1], 0, 0, 0);
        acc[3][1] = __builtin_amdgcn_mfma_f32_16x16x32_bf16(a3, bb1, acc[3][1], 0, 0, 0);
    }
    __syncthreads();

    #pragma unroll
    for (int j = 0; j < 2; ++j) {
        int n = wave * 32 + j * 16 + col16;
        float bias = sb1[n];
        #pragma unroll
        for (int mt = 0; mt < 4; ++mt) {
            #pragma unroll
            for (int r = 0; r < 4; ++r) {
                int m = mt * 16 + quad * 4 + r;
                sH1[m * PAD1 + n] = (__bf16)fmaxf(acc[mt][j][r] + bias, 0.f);
            }
        }
    }
    __syncthreads();

    v4f acc2[4];
    #pragma unroll
    for (int mt = 0; mt < 4; ++mt) acc2[mt] = zero4;
    const __bf16* w2p = wt2 + (size_t)(wave * 16 + col16) * H1DIM;
    #pragma unroll
    for (int ks = 0; ks < 4; ++ks) {
        int k0 = ks * 32 + quad * 8;
        v8bf bb = *(const v8bf*)&w2p[k0];
        #pragma unroll
        for (int mt = 0; mt < 4; ++mt) {
            v8bf aa = *(const v8bf*)&sH1[(mt * 16 + col16) * PAD1 + k0];
            acc2[mt] = __builtin_amdgcn_mfma_f32_16x16x32_bf16(aa, bb, acc2[mt], 0, 0, 0);
        }
    }
    {
        int n = wave * 16 + col16;
        float bias = sb2[n];
        #pragma unroll
        for (int mt = 0; mt < 4; ++mt) {
            #pragma unroll
            for (int rr = 0; rr < 4; ++rr) {
                int m = mt * 16 + quad * 4 + rr;
                sH2[m * PAD2 + n] = (__bf16)fmaxf(acc2[mt][rr] + bias, 0.f);
            }
        }
    }
    __syncthreads();
    {
        int row = tid >> 2, q = tid & 3;
        float s = 0.f;
        #pragma unroll
        for (int kk = 0; kk < 16; ++kk) {
            int k = q * 16 + kk;
            s += (float)sH2[row * PAD2 + k] * sw3[k];
        }
        s += __shfl_xor(s, 1);
        s += __shfl_xor(s, 2);
        if (q == 0) {
            float x = s + sb3s;
            out[e0 + row] = fmaxf(x, 0.f) + log1pf(expf(-fabsf(x)));
        }
    }
}

extern "C" void kernel_launch(void* const* d_in, const int* in_sizes, int n_in,
                              void* d_out, int out_size, void* d_ws, size_t ws_size,
                              hipStream_t stream) {
    const float* z     = (const float*)d_in[0];
    const int*   eidx  = (const int*)d_in[1];
    const int*   btyp  = (const int*)d_in[2];
    const float* embed = (const float*)d_in[3];
    const float* W1    = (const float*)d_in[4];
    const float* b1    = (const float*)d_in[5];
    const float* W2    = (const float*)d_in[6];
    const float* b2    = (const float*)d_in[7];
    const float* W3    = (const float*)d_in[8];
    const float* b3    = (const float*)d_in[9];
    float* out = (float*)d_out;
    __bf16* ws = (__bf16*)d_ws;

    if (ws_size >= WS_SPLIT) {
        prep_split<<<167, 256, 0, stream>>>(W1, W2, embed, b1, ws);
        node_gemm<<<NGBLK, 256, 0, stream>>>(z, ws, ws);
        edge_kernel<<<EBLK, 256, 0, stream>>>(eidx, btyp, b2, W3, b3, ws, out);
    } else {
        prep_mono<<<(DIN * H1DIM + 255) / 256, 256, 0, stream>>>(W1, W2, ws);
        fused_mono<<<EBLK, 256, 0, stream>>>(z, eidx, btyp, embed,
                                             b1, b2, W3, b3, ws, out);
    }
}